// Round 1
// baseline (482.826 us; speedup 1.0000x reference)
//
#include <hip/hip_runtime.h>
#include <hip/hip_bf16.h>

// Swin block fp32 I/O, MFMA bf16 compute. B=8,H=W=128,C=192,NH=6,hd=32,WS=8,SS=4.
// Round 6: 2-phase double-buffered weight staging (prefetch chunk kc+1 while
// computing kc) in k_attn and k_mlp; biases staged to LDS so no mid-loop global
// load forces a vmcnt(0) drain of the prefetch.
//  k_prep: weight images (group-contiguous qkv, transposed, k-padded) + bias/mask
//          w2T now [24][192][40] (32-k chunks, 8-elem pad -> free 2-way LDS reads)
//  k_attn: per-window qkv (9x32-col double-buffered chunks) -> attn -> O scratch
//  k_proj: O @ projW + x -> xres   (projT staged once per block)
//  k_mlp : LN -> MLP1 -> GELU -> MLP2 -> +xres (24x32-hidden double-buffered)
//
// MFMA 16x16x32 bf16 layouts (HW-verified):
//   A: a[j] = A[m=lane&15][k=quad*8+j]
//   B: b[j] = B[k=quad*8+j][n=lane&15]
//   D: d[reg] = D[row=quad*4+reg][col=lane&15]

typedef __hip_bfloat16 bf16;
typedef __attribute__((ext_vector_type(8))) short bfrag;
typedef __attribute__((ext_vector_type(4))) float ffrag;

union bfu { bf16 h[8]; bfrag v; };

__device__ __forceinline__ float b2f(bf16 v) { return __bfloat162float(v); }
__device__ __forceinline__ bf16  f2b(float v) { return __float2bfloat16(v); }

#define MFMA(a, b, c) __builtin_amdgcn_mfma_f32_16x16x32_bf16((a), (b), (c), 0, 0, 0)

// workspace byte offsets
#define WS_XRES  0ULL
#define WS_OG    100663296ULL                  // bf16 [131072][192] attention output
#define WS_QKVTG 150994944ULL                  // bf16 [2][320][200] group-contiguous qkv_w^T
#define WS_QBG   151250944ULL                  // f32  [2][320] group-contiguous qkv_b
#define WS_PROJT 151253504ULL                  // bf16 [192][200]
#define WS_W1T   151330304ULL                  // bf16 [768][200]
#define WS_W2T   151637504ULL                  // bf16 [24][192][40]
#define WS_SB    152006144ULL                  // bf16 [4][6][64][64]

// async contiguous global->LDS copy; 256 threads; handles non-multiple-of-1024 tails
__device__ __forceinline__ void stage_lds(const void* g, void* l, int nbytes, int t) {
    const int lane16 = (t & 63) * 16;
    for (int base = (t >> 6) * 1024; base < nbytes; base += 4096) {
        if (base + lane16 < nbytes) {
            __builtin_amdgcn_global_load_lds(
                (const __attribute__((address_space(1))) void*)((const char*)g + base + lane16),
                (__attribute__((address_space(3))) void*)((char*)l + base),
                16, 0, 0);
        }
    }
}

__device__ __forceinline__ float gelu_t(float x) {
    float y = x * (1.5957691216057308f + 0.07135481627f * x * x);
    return x * (1.f / (1.f + __expf(-y)));
}

// ---------------------------------------------------------------------------
// k_prep: 2357 x 256 covers 603264 elements
// ---------------------------------------------------------------------------
__global__ __launch_bounds__(256) void k_prep(
    const float* __restrict__ qkv_w, const float* __restrict__ qkv_b,
    const float* __restrict__ proj_w, const float* __restrict__ w1,
    const float* __restrict__ w2, const float* __restrict__ rpb,
    char* __restrict__ ws)
{
    int i = blockIdx.x * 256 + threadIdx.x;
    bf16*  qkvTg = (bf16*)(ws + WS_QKVTG);
    float* qbg   = (float*)(ws + WS_QBG);
    bf16*  projT = (bf16*)(ws + WS_PROJT);
    bf16*  w1T   = (bf16*)(ws + WS_W1T);
    bf16*  w2T   = (bf16*)(ws + WS_W2T);
    bf16*  sbB   = (bf16*)(ws + WS_SB);

    if (i < 128000) {                          // qkvTg [2][320][200]
        int g = i / 64000, rem = i % 64000;
        int c = rem / 200, k = rem % 200;
        float v = 0.f;
        if (k < 192) {
            if (c < 96)       v = qkv_w[k * 576 + g * 96 + c];
            else if (c < 192) v = qkv_w[k * 576 + 192 + g * 96 + (c - 96)];
            else if (c < 288) v = qkv_w[k * 576 + 384 + g * 96 + (c - 192)];
        }
        qkvTg[i] = f2b(v);
    } else if (i < 128640) {                   // qbg [2][320]
        int j = i - 128000;
        int g = j / 320, c = j % 320;
        float v = 0.f;
        if (c < 96)       v = qkv_b[g * 96 + c];
        else if (c < 192) v = qkv_b[192 + g * 96 + (c - 96)];
        else if (c < 288) v = qkv_b[384 + g * 96 + (c - 192)];
        qbg[j] = v;
    } else if (i < 167040) {                   // projT [192][200]
        int j = i - 128640;
        int c = j / 200, k = j % 200;
        projT[j] = f2b(k < 192 ? proj_w[k * 192 + c] : 0.f);
    } else if (i < 320640) {                   // w1T [768][200]
        int j = i - 167040;
        int c = j / 200, k = j % 200;
        w1T[j] = f2b(k < 192 ? w1[k * 768 + c] : 0.f);
    } else if (i < 504960) {                   // w2T [24][192][40]
        int j = i - 320640;
        int kc = j / 7680, r = (j % 7680) / 40, kk = j % 40;
        w2T[j] = f2b(kk < 32 ? w2[(kc * 32 + kk) * 192 + r] : 0.f);
    } else if (i < 603264) {                   // sbB [4][6][64][64]
        int j = i - 504960;
        int cls = j / 24576, h = (j % 24576) / 4096;
        int ii = (j % 4096) / 64, jj = j % 64;
        int ri = ii >> 3, ci = ii & 7, rj = jj >> 3, cj = jj & 7;
        float bias = rpb[(((ri - rj + 7) * 15) + (ci - cj + 7)) * 6 + h];
        int clsR = cls >> 1, clsC = cls & 1;
        int regi = (clsR ? (ri < 4 ? 1 : 2) : 0) * 3 + (clsC ? (ci < 4 ? 1 : 2) : 0);
        int regj = (clsR ? (rj < 4 ? 1 : 2) : 0) * 3 + (clsC ? (cj < 4 ? 1 : 2) : 0);
        sbB[j] = f2b(bias + (regi == regj ? 0.f : -100.f));
    }
}

// ---------------------------------------------------------------------------
// k_attn: one window/block, 4 waves x 16 rows. qkv weights: 9x32-col chunks,
// double-buffered, prefetched one chunk ahead. LDS 77824 -> 2 blocks/CU.
// ---------------------------------------------------------------------------
__global__ __launch_bounds__(256, 2) void k_attn(
    const float* __restrict__ x, const char* __restrict__ ws,
    bf16* __restrict__ Og)
{
    __shared__ __align__(16) unsigned char smem[77824];
    bf16*  sWb = (bf16*)(smem);            // 2 x [32][200] double-buffered chunk
    bf16*  sQ  = (bf16*)(smem + 25600);    // [64][104]
    bf16*  sK  = (bf16*)(smem + 38912);    // [64][104]
    bf16*  sVT = (bf16*)(smem + 52224);    // [96][72]
    bf16*  sP  = (bf16*)(smem + 66048);    // [4][16][72]
    float* sQB = (float*)(smem + 75264);   // [640] qkv bias (both groups)

    const bf16*  qkvTg = (const bf16*)(ws + WS_QKVTG);
    const float* qbg   = (const float*)(ws + WS_QBG);
    const bf16*  sbB   = (const bf16*)(ws + WS_SB);

    const int t    = threadIdx.x;
    const int lane = t & 63, quad = lane >> 4, l15 = lane & 15;
    const int wave = t >> 6, r0 = wave * 16;
    const int win = blockIdx.x;
    const int b   = win >> 8;
    const int wi  = win & 255;
    const int wh  = wi >> 4, wwi = wi & 15;

    // prologue staging: biases + first chunk (hidden under aX gather/convert)
    stage_lds(qbg, smem + 75264, 2560, t);
    stage_lds(qkvTg, sWb, 12800, t);

    // A-frags of gathered x window, direct from global (fp32 -> bf16)
    bfrag aX[6];
    {
        int row = r0 + l15;
        int rr = row >> 3, cc = row & 7;
        int hs  = (wh * 8 + rr + 4) & 127;
        int wsx = (wwi * 8 + cc + 4) & 127;
        const float* xrow = x + ((size_t)(b * 16384 + hs * 128 + wsx)) * 192;
        #pragma unroll
        for (int kb = 0; kb < 6; kb++) {
            float4 f0 = *(const float4*)(xrow + kb * 32 + quad * 8);
            float4 f1 = *(const float4*)(xrow + kb * 32 + quad * 8 + 4);
            bfu u;
            u.h[0] = f2b(f0.x); u.h[1] = f2b(f0.y); u.h[2] = f2b(f0.z); u.h[3] = f2b(f0.w);
            u.h[4] = f2b(f1.x); u.h[5] = f2b(f1.y); u.h[6] = f2b(f1.z); u.h[7] = f2b(f1.w);
            aX[kb] = u.v;
        }
    }

    const int cls = ((wh == 15) ? 2 : 0) + ((wwi == 15) ? 1 : 0);
    const bf16* bBc = sbB + (size_t)cls * 24576;
    bf16* sPw = sP + wave * 16 * 72;

    __syncthreads();                           // chunk0 + biases staged

    int pb = 0;
    for (int g = 0; g < 2; g++) {
        // ---- qkv for head group g: 9 chunks of 32 cols, 2-phase pipeline ----
        for (int c = 0; c < 9; c++) {
            if (c < 8)
                stage_lds(qkvTg + (size_t)(g * 320 + (c + 1) * 32) * 200,
                          sWb + (pb ^ 1) * 6400, 12800, t);
            else if (g == 0)
                stage_lds(qkvTg + (size_t)320 * 200,
                          sWb + (pb ^ 1) * 6400, 12800, t);
            const bf16* sW = sWb + pb * 6400;
            #pragma unroll
            for (int ct = 0; ct < 2; ct++) {
                int c0 = c * 32 + ct * 16;
                bfrag bw[6];
                #pragma unroll
                for (int kb = 0; kb < 6; kb++)
                    bw[kb] = *(const bfrag*)&sW[(ct * 16 + l15) * 200 + kb * 32 + quad * 8];
                ffrag acc = {0.f, 0.f, 0.f, 0.f};
                #pragma unroll
                for (int kb = 0; kb < 6; kb++) acc = MFMA(aX[kb], bw[kb], acc);
                float bias = sQB[g * 320 + c0 + l15];
                #pragma unroll
                for (int reg = 0; reg < 4; reg++) {
                    int r = r0 + quad * 4 + reg;
                    float v = acc[reg] + bias;
                    if (c0 < 96)       sQ[r * 104 + c0 + l15] = f2b(v);
                    else if (c0 < 192) sK[r * 104 + (c0 - 96) + l15] = f2b(v);
                    else               sVT[(c0 - 192 + l15) * 72 + r] = f2b(v);
                }
            }
            __syncthreads();                   // drains prefetch; chunk c+1 ready
            pb ^= 1;
        }
        // ---- attention heads g*3 .. g*3+2 (no staging in flight here) ----
        for (int hl = 0; hl < 3; hl++) {
            int h = g * 3 + hl;
            bfrag aQ = *(const bfrag*)&sQ[(r0 + l15) * 104 + hl * 32 + quad * 8];
            ffrag Sf[4];
            #pragma unroll
            for (int jt = 0; jt < 4; jt++) {
                bfrag bK = *(const bfrag*)&sK[(jt * 16 + l15) * 104 + hl * 32 + quad * 8];
                ffrag z = {0.f, 0.f, 0.f, 0.f};
                Sf[jt] = MFMA(aQ, bK, z);
            }
            const bf16* bb = bBc + h * 4096 + (r0 + quad * 4) * 64 + l15;
            #pragma unroll
            for (int jt = 0; jt < 4; jt++)
                #pragma unroll
                for (int reg = 0; reg < 4; reg++)
                    Sf[jt][reg] = Sf[jt][reg] * 0.1767766952966369f
                                + b2f(bb[reg * 64 + jt * 16]);
            #pragma unroll
            for (int reg = 0; reg < 4; reg++) {
                float m = fmaxf(fmaxf(Sf[0][reg], Sf[1][reg]), fmaxf(Sf[2][reg], Sf[3][reg]));
                m = fmaxf(m, __shfl_xor(m, 1)); m = fmaxf(m, __shfl_xor(m, 2));
                m = fmaxf(m, __shfl_xor(m, 4)); m = fmaxf(m, __shfl_xor(m, 8));
                float s = 0.f;
                #pragma unroll
                for (int jt = 0; jt < 4; jt++) { Sf[jt][reg] = __expf(Sf[jt][reg] - m); s += Sf[jt][reg]; }
                s += __shfl_xor(s, 1); s += __shfl_xor(s, 2);
                s += __shfl_xor(s, 4); s += __shfl_xor(s, 8);
                float inv = 1.f / s;
                int prow = (quad * 4 + reg) * 72;
                #pragma unroll
                for (int jt = 0; jt < 4; jt++)
                    sPw[prow + jt * 16 + l15] = f2b(Sf[jt][reg] * inv);
            }
            bfrag aP0 = *(const bfrag*)&sPw[l15 * 72 + quad * 8];
            bfrag aP1 = *(const bfrag*)&sPw[l15 * 72 + 32 + quad * 8];
            #pragma unroll
            for (int ct = 0; ct < 2; ct++) {
                bfrag bV0 = *(const bfrag*)&sVT[(hl * 32 + ct * 16 + l15) * 72 + quad * 8];
                bfrag bV1 = *(const bfrag*)&sVT[(hl * 32 + ct * 16 + l15) * 72 + 32 + quad * 8];
                ffrag z = {0.f, 0.f, 0.f, 0.f};
                ffrag o = MFMA(aP1, bV1, MFMA(aP0, bV0, z));
                #pragma unroll
                for (int reg = 0; reg < 4; reg++)
                    Og[((size_t)win * 64 + r0 + quad * 4 + reg) * 192 + h * 32 + ct * 16 + l15]
                        = f2b(o[reg]);
            }
        }
        __syncthreads();                       // attn reads done before g1 writes
    }
}

// ---------------------------------------------------------------------------
// k_proj: 128 rows (2 windows)/block, 4 waves x 32 rows (rt=2).
// projT staged ONCE (76800 B), 1 barrier. -> xres (reverse-shift + residual)
// ---------------------------------------------------------------------------
__global__ __launch_bounds__(256, 2) void k_proj(
    const float* __restrict__ x, const float* __restrict__ proj_b,
    const char* __restrict__ ws, float* __restrict__ xres)
{
    __shared__ __align__(16) bf16 sWp[192 * 200];   // 76800 B

    const bf16* projT = (const bf16*)(ws + WS_PROJT);
    const bf16* Og    = (const bf16*)(ws + WS_OG);

    const int t    = threadIdx.x;
    const int lane = t & 63, quad = lane >> 4, l15 = lane & 15;
    const int wave = t >> 6, r0 = wave * 32;
    const size_t row0 = (size_t)blockIdx.x * 128;

    stage_lds(projT, sWp, 76800, t);

    // A-frags of O (global, bf16, contiguous 16B)
    bfrag aO[2][6];
    #pragma unroll
    for (int rt = 0; rt < 2; rt++)
        #pragma unroll
        for (int kb = 0; kb < 6; kb++)
            aO[rt][kb] = *(const bfrag*)&Og[(row0 + r0 + rt * 16 + l15) * 192 + kb * 32 + quad * 8];

    // token scatter addresses (reverse shift)
    size_t tokb[2][4];
    #pragma unroll
    for (int rt = 0; rt < 2; rt++)
        #pragma unroll
        for (int reg = 0; reg < 4; reg++) {
            int n = r0 + rt * 16 + quad * 4 + reg;
            int w2 = (int)(blockIdx.x * 2) + (n >> 6);
            int nl = n & 63;
            int b = w2 >> 8, wi = w2 & 255;
            int wh = wi >> 4, wwi = wi & 15;
            int sr = wh * 8 + (nl >> 3), sc = wwi * 8 + (nl & 7);
            int h2 = (sr + 4) & 127, w2c = (sc + 4) & 127;
            tokb[rt][reg] = ((size_t)(b * 16384 + h2 * 128 + w2c)) * 192;
        }

    __syncthreads();

    ffrag acc[2][12];
    #pragma unroll
    for (int rt = 0; rt < 2; rt++)
        #pragma unroll
        for (int ct = 0; ct < 12; ct++)
            acc[rt][ct] = (ffrag){0.f, 0.f, 0.f, 0.f};

    #pragma unroll
    for (int ct = 0; ct < 12; ct++) {
        bfrag bw[6];
        #pragma unroll
        for (int kb = 0; kb < 6; kb++)
            bw[kb] = *(const bfrag*)&sWp[(ct * 16 + l15) * 200 + kb * 32 + quad * 8];
        #pragma unroll
        for (int rt = 0; rt < 2; rt++)
            #pragma unroll
            for (int kb = 0; kb < 6; kb++)
                acc[rt][ct] = MFMA(aO[rt][kb], bw[kb], acc[rt][ct]);
    }

    #pragma unroll
    for (int rt = 0; rt < 2; rt++)
        #pragma unroll
        for (int ct = 0; ct < 12; ct++) {
            int col = ct * 16 + l15;
            float pb = proj_b[col];
            #pragma unroll
            for (int reg = 0; reg < 4; reg++) {
                size_t gi = tokb[rt][reg] + col;
                xres[gi] = acc[rt][ct][reg] + pb + x[gi];
            }
        }
}

// ---------------------------------------------------------------------------
// k_mlp: 128 rows/block, 4 waves x 32 rows (rt=2). 24 chunks of 32 hidden,
// double-buffered w1/w2 staging prefetched one chunk ahead. b1 in LDS.
// LDS 69632 -> 2 blocks/CU.
// ---------------------------------------------------------------------------
__global__ __launch_bounds__(256, 2) void k_mlp(
    const float* __restrict__ xres, const float* __restrict__ g,
    const float* __restrict__ bb, const float* __restrict__ b1,
    const float* __restrict__ b2, const char* __restrict__ ws,
    float* __restrict__ out)
{
    __shared__ __align__(16) unsigned char smem[69632];
    bf16*  w1base = (bf16*)(smem);           // 2 x [32][200] (12800 B each)
    bf16*  w2base = (bf16*)(smem + 25600);   // 2 x [192][40] (15360 B each)
    bf16*  hS     = (bf16*)(smem + 56320);   // [4][32][40] (10240 B)
    float* sB1f   = (float*)(smem + 66560);  // [768] (3072 B)
    bf16*  U      = (bf16*)(smem);           // xn [128][200] (prologue only)

    const bf16* w1T = (const bf16*)(ws + WS_W1T);
    const bf16* w2T = (const bf16*)(ws + WS_W2T);

    const int t    = threadIdx.x;
    const int lane = t & 63, quad = lane >> 4, l15 = lane & 15;
    const int wave = t >> 6, r0 = wave * 32;
    const size_t row0 = (size_t)blockIdx.x * 128;

    stage_lds(b1, smem + 66560, 3072, t);    // b1 -> LDS (region disjoint from xn)

    // ---- wave-local LayerNorm -> xn (bf16, U) ----
    #pragma unroll
    for (int p = 0; p < 2; p++) {
        int row = r0 + p * 16 + l15;
        const float4* src = (const float4*)(xres + (row0 + row) * 192 + quad * 48);
        float v[48];
        float s = 0.f, sq = 0.f;
        #pragma unroll
        for (int u = 0; u < 12; u++) {
            float4 f = src[u];
            v[u*4] = f.x; v[u*4+1] = f.y; v[u*4+2] = f.z; v[u*4+3] = f.w;
            s  += f.x + f.y + f.z + f.w;
            sq += f.x*f.x + f.y*f.y + f.z*f.z + f.w*f.w;
        }
        s  += __shfl_xor(s, 16);  s  += __shfl_xor(s, 32);
        sq += __shfl_xor(sq, 16); sq += __shfl_xor(sq, 32);
        float mean = s * (1.f / 192.f);
        float var  = sq * (1.f / 192.f) - mean * mean;
        float rstd = rsqrtf(var + 1e-5f);
        __hip_bfloat162* dst = (__hip_bfloat162*)&U[row * 200 + quad * 48];
        #pragma unroll
        for (int u = 0; u < 24; u++) {
            int c = quad * 48 + u * 2;
            float a0 = (v[u*2]   - mean) * rstd * g[c]     + bb[c];
            float a1 = (v[u*2+1] - mean) * rstd * g[c + 1] + bb[c + 1];
            dst[u] = __float22bfloat162_rn({a0, a1});
        }
    }

    // A-frags of xn (own rows; within-wave RAW)
    bfrag aX[2][6];
    #pragma unroll
    for (int rt = 0; rt < 2; rt++)
        #pragma unroll
        for (int kb = 0; kb < 6; kb++)
            aX[rt][kb] = *(const bfrag*)&U[(r0 + rt*16 + l15) * 200 + kb*32 + quad*8];

    __syncthreads();                         // everyone done reading xn region

    // stage chunk 0 (overlays xn region — safe after barrier)
    stage_lds(w1T, w1base, 12800, t);
    stage_lds(w2T, w2base, 15360, t);
    __syncthreads();                         // chunk 0 landed

    bf16* hs_w = hS + wave * 32 * 40;

    ffrag oacc[2][12];
    #pragma unroll
    for (int rt = 0; rt < 2; rt++)
        #pragma unroll
        for (int ct = 0; ct < 12; ct++)
            oacc[rt][ct] = (ffrag){0.f, 0.f, 0.f, 0.f};

    for (int kc = 0; kc < 24; kc++) {
        const int p = kc & 1;
        const bf16* w1c = w1base + p * 6400;
        const bf16* w2c = w2base + p * 7680;
        if (kc < 23) {                       // prefetch next chunk into other buffer
            stage_lds(w1T + (size_t)(kc + 1) * 6400, w1base + (p ^ 1) * 6400, 12800, t);
            stage_lds(w2T + (size_t)(kc + 1) * 7680, w2base + (p ^ 1) * 7680, 15360, t);
        }

        // MLP1 (32 hidden cols) + GELU -> hS (own rows)
        #pragma unroll
        for (int ct = 0; ct < 2; ct++) {
            bfrag bw[6];
            #pragma unroll
            for (int kb = 0; kb < 6; kb++)
                bw[kb] = *(const bfrag*)&w1c[(ct*16 + l15) * 200 + kb*32 + quad*8];
            float bias = sB1f[kc * 32 + ct * 16 + l15];
            #pragma unroll
            for (int rt = 0; rt < 2; rt++) {
                ffrag a = {0.f, 0.f, 0.f, 0.f};
                #pragma unroll
                for (int kb = 0; kb < 6; kb++) a = MFMA(aX[rt][kb], bw[kb], a);
                #pragma unroll
                for (int reg = 0; reg < 4; reg++)
                    hs_w[(rt*16 + quad*4 + reg) * 40 + ct*16 + l15] =
                        f2b(gelu_t(a[reg] + bias));
            }
        }
        // MLP2 over this 32-k chunk
        bfrag aH[2];
        #pragma unroll
        for (int rt = 0; rt < 2; rt++)
            aH[rt] = *(const bfrag*)&hs_w[(rt*16 + l15) * 40 + quad*8];
        #pragma unroll
        for (int ct = 0; ct < 12; ct++) {
            bfrag bw2 = *(const bfrag*)&w2c[(ct*16 + l15) * 40 + quad*8];
            #pragma unroll
            for (int rt = 0; rt < 2; rt++)
                oacc[rt][ct] = MFMA(aH[rt], bw2, oacc[rt][ct]);
        }
        __syncthreads();                     // drains prefetch; next chunk ready
    }

    // ---- epilogue: out = xres + mlp + b2 ----
    #pragma unroll
    for (int rt = 0; rt < 2; rt++)
        #pragma unroll
        for (int ct = 0; ct < 12; ct++) {
            int col = ct * 16 + l15;
            float b2v = b2[col];
            #pragma unroll
            for (int reg = 0; reg < 4; reg++) {
                size_t gi = (row0 + r0 + rt*16 + quad*4 + reg) * 192 + col;
                out[gi] = xres[gi] + oacc[rt][ct][reg] + b2v;
            }
        }
}

// ---------------------------------------------------------------------------
extern "C" void kernel_launch(void* const* d_in, const int* in_sizes, int n_in,
                              void* d_out, int out_size, void* d_ws, size_t ws_size,
                              hipStream_t stream)
{
    (void)in_sizes; (void)n_in; (void)out_size; (void)ws_size;

    const float* x      = (const float*)d_in[0];
    const float* qkv_w  = (const float*)d_in[1];
    const float* qkv_b  = (const float*)d_in[2];
    const float* proj_w = (const float*)d_in[3];
    const float* proj_b = (const float*)d_in[4];
    const float* rpb    = (const float*)d_in[5];
    const float* n2g    = (const float*)d_in[6];
    const float* n2b    = (const float*)d_in[7];
    const float* w1     = (const float*)d_in[8];
    const float* b1     = (const float*)d_in[9];
    const float* w2     = (const float*)d_in[10];
    const float* b2     = (const float*)d_in[11];

    char*  ws   = (char*)d_ws;
    float* xres = (float*)(ws + WS_XRES);
    bf16*  Og   = (bf16*)(ws + WS_OG);
    float* out  = (float*)d_out;

    hipLaunchKernelGGL(k_prep, dim3(2357), dim3(256), 0, stream,
                       qkv_w, qkv_b, proj_w, w1, w2, rpb, ws);
    hipLaunchKernelGGL(k_attn, dim3(2048), dim3(256), 0, stream,
                       x, ws, Og);
    hipLaunchKernelGGL(k_proj, dim3(1024), dim3(256), 0, stream,
                       x, proj_b, ws, xres);
    hipLaunchKernelGGL(k_mlp,  dim3(1024), dim3(256), 0, stream,
                       xres, n2g, n2b, b1, b2, ws, out);
}

// Round 2
// 474.590 us; speedup vs baseline: 1.0174x; 1.0174x over previous
//
#include <hip/hip_runtime.h>
#include <hip/hip_bf16.h>

// Swin block fp32 I/O, MFMA bf16 compute. B=8,H=W=128,C=192,NH=6,hd=32,WS=8,SS=4.
// Round 7: k_mlp main loop converted to counted-vmcnt pipeline (T3+T4):
//   raw s_barrier + asm "s_waitcnt vmcnt(8)" so the 8 prefetch loads of chunk
//   kc+1 stay in flight across the barrier (no compiler vmcnt(0) drain).
//   Staging uses per-wave-contiguous quarters -> uniform 4+4 issues/wave.
// k_attn / k_proj / k_prep unchanged from round 6.
//
// MFMA 16x16x32 bf16 layouts (HW-verified):
//   A: a[j] = A[m=lane&15][k=quad*8+j]
//   B: b[j] = B[k=quad*8+j][n=lane&15]
//   D: d[reg] = D[row=quad*4+reg][col=lane&15]

typedef __hip_bfloat16 bf16;
typedef __attribute__((ext_vector_type(8))) short bfrag;
typedef __attribute__((ext_vector_type(4))) float ffrag;

union bfu { bf16 h[8]; bfrag v; };

__device__ __forceinline__ float b2f(bf16 v) { return __bfloat162float(v); }
__device__ __forceinline__ bf16  f2b(float v) { return __float2bfloat16(v); }

#define MFMA(a, b, c) __builtin_amdgcn_mfma_f32_16x16x32_bf16((a), (b), (c), 0, 0, 0)

// workspace byte offsets
#define WS_XRES  0ULL
#define WS_OG    100663296ULL                  // bf16 [131072][192] attention output
#define WS_QKVTG 150994944ULL                  // bf16 [2][320][200] group-contiguous qkv_w^T
#define WS_QBG   151250944ULL                  // f32  [2][320] group-contiguous qkv_b
#define WS_PROJT 151253504ULL                  // bf16 [192][200]
#define WS_W1T   151330304ULL                  // bf16 [768][200]
#define WS_W2T   151637504ULL                  // bf16 [24][192][40]
#define WS_SB    152006144ULL                  // bf16 [4][6][64][64]

// async contiguous global->LDS copy; 256 threads; wave-strided (non-uniform
// per-wave issue counts -- only for kernels using __syncthreads semantics)
__device__ __forceinline__ void stage_lds(const void* g, void* l, int nbytes, int t) {
    const int lane16 = (t & 63) * 16;
    for (int base = (t >> 6) * 1024; base < nbytes; base += 4096) {
        if (base + lane16 < nbytes) {
            __builtin_amdgcn_global_load_lds(
                (const __attribute__((address_space(1))) void*)((const char*)g + base + lane16),
                (__attribute__((address_space(3))) void*)((char*)l + base),
                16, 0, 0);
        }
    }
}

// async copy with per-wave CONTIGUOUS quarters -> every wave issues exactly
// ceil((nbytes/4)/1024) global_load_lds ops (uniform vmcnt accounting).
// nbytes/4 must be a multiple of 16.
__device__ __forceinline__ void stage_lds_q(const void* g, void* l, int nbytes, int t) {
    const int lane16 = (t & 63) * 16;
    const int sub = nbytes >> 2;
    const int off = (t >> 6) * sub;
    for (int base = 0; base < sub; base += 1024) {
        if (base + lane16 < sub) {
            __builtin_amdgcn_global_load_lds(
                (const __attribute__((address_space(1))) void*)((const char*)g + off + base + lane16),
                (__attribute__((address_space(3))) void*)((char*)l + off + base),
                16, 0, 0);
        }
    }
}

__device__ __forceinline__ float gelu_t(float x) {
    float y = x * (1.5957691216057308f + 0.07135481627f * x * x);
    return x * (1.f / (1.f + __expf(-y)));
}

// ---------------------------------------------------------------------------
// k_prep: 2357 x 256 covers 603264 elements
// ---------------------------------------------------------------------------
__global__ __launch_bounds__(256) void k_prep(
    const float* __restrict__ qkv_w, const float* __restrict__ qkv_b,
    const float* __restrict__ proj_w, const float* __restrict__ w1,
    const float* __restrict__ w2, const float* __restrict__ rpb,
    char* __restrict__ ws)
{
    int i = blockIdx.x * 256 + threadIdx.x;
    bf16*  qkvTg = (bf16*)(ws + WS_QKVTG);
    float* qbg   = (float*)(ws + WS_QBG);
    bf16*  projT = (bf16*)(ws + WS_PROJT);
    bf16*  w1T   = (bf16*)(ws + WS_W1T);
    bf16*  w2T   = (bf16*)(ws + WS_W2T);
    bf16*  sbB   = (bf16*)(ws + WS_SB);

    if (i < 128000) {                          // qkvTg [2][320][200]
        int g = i / 64000, rem = i % 64000;
        int c = rem / 200, k = rem % 200;
        float v = 0.f;
        if (k < 192) {
            if (c < 96)       v = qkv_w[k * 576 + g * 96 + c];
            else if (c < 192) v = qkv_w[k * 576 + 192 + g * 96 + (c - 96)];
            else if (c < 288) v = qkv_w[k * 576 + 384 + g * 96 + (c - 192)];
        }
        qkvTg[i] = f2b(v);
    } else if (i < 128640) {                   // qbg [2][320]
        int j = i - 128000;
        int g = j / 320, c = j % 320;
        float v = 0.f;
        if (c < 96)       v = qkv_b[g * 96 + c];
        else if (c < 192) v = qkv_b[192 + g * 96 + (c - 96)];
        else if (c < 288) v = qkv_b[384 + g * 96 + (c - 192)];
        qbg[j] = v;
    } else if (i < 167040) {                   // projT [192][200]
        int j = i - 128640;
        int c = j / 200, k = j % 200;
        projT[j] = f2b(k < 192 ? proj_w[k * 192 + c] : 0.f);
    } else if (i < 320640) {                   // w1T [768][200]
        int j = i - 167040;
        int c = j / 200, k = j % 200;
        w1T[j] = f2b(k < 192 ? w1[k * 768 + c] : 0.f);
    } else if (i < 504960) {                   // w2T [24][192][40]
        int j = i - 320640;
        int kc = j / 7680, r = (j % 7680) / 40, kk = j % 40;
        w2T[j] = f2b(kk < 32 ? w2[(kc * 32 + kk) * 192 + r] : 0.f);
    } else if (i < 603264) {                   // sbB [4][6][64][64]
        int j = i - 504960;
        int cls = j / 24576, h = (j % 24576) / 4096;
        int ii = (j % 4096) / 64, jj = j % 64;
        int ri = ii >> 3, ci = ii & 7, rj = jj >> 3, cj = jj & 7;
        float bias = rpb[(((ri - rj + 7) * 15) + (ci - cj + 7)) * 6 + h];
        int clsR = cls >> 1, clsC = cls & 1;
        int regi = (clsR ? (ri < 4 ? 1 : 2) : 0) * 3 + (clsC ? (ci < 4 ? 1 : 2) : 0);
        int regj = (clsR ? (rj < 4 ? 1 : 2) : 0) * 3 + (clsC ? (cj < 4 ? 1 : 2) : 0);
        sbB[j] = f2b(bias + (regi == regj ? 0.f : -100.f));
    }
}

// ---------------------------------------------------------------------------
// k_attn: one window/block, 4 waves x 16 rows. qkv weights: 9x32-col chunks,
// double-buffered, prefetched one chunk ahead. LDS 77824 -> 2 blocks/CU.
// ---------------------------------------------------------------------------
__global__ __launch_bounds__(256, 2) void k_attn(
    const float* __restrict__ x, const char* __restrict__ ws,
    bf16* __restrict__ Og)
{
    __shared__ __align__(16) unsigned char smem[77824];
    bf16*  sWb = (bf16*)(smem);            // 2 x [32][200] double-buffered chunk
    bf16*  sQ  = (bf16*)(smem + 25600);    // [64][104]
    bf16*  sK  = (bf16*)(smem + 38912);    // [64][104]
    bf16*  sVT = (bf16*)(smem + 52224);    // [96][72]
    bf16*  sP  = (bf16*)(smem + 66048);    // [4][16][72]
    float* sQB = (float*)(smem + 75264);   // [640] qkv bias (both groups)

    const bf16*  qkvTg = (const bf16*)(ws + WS_QKVTG);
    const float* qbg   = (const float*)(ws + WS_QBG);
    const bf16*  sbB   = (const bf16*)(ws + WS_SB);

    const int t    = threadIdx.x;
    const int lane = t & 63, quad = lane >> 4, l15 = lane & 15;
    const int wave = t >> 6, r0 = wave * 16;
    const int win = blockIdx.x;
    const int b   = win >> 8;
    const int wi  = win & 255;
    const int wh  = wi >> 4, wwi = wi & 15;

    // prologue staging: biases + first chunk (hidden under aX gather/convert)
    stage_lds(qbg, smem + 75264, 2560, t);
    stage_lds(qkvTg, sWb, 12800, t);

    // A-frags of gathered x window, direct from global (fp32 -> bf16)
    bfrag aX[6];
    {
        int row = r0 + l15;
        int rr = row >> 3, cc = row & 7;
        int hs  = (wh * 8 + rr + 4) & 127;
        int wsx = (wwi * 8 + cc + 4) & 127;
        const float* xrow = x + ((size_t)(b * 16384 + hs * 128 + wsx)) * 192;
        #pragma unroll
        for (int kb = 0; kb < 6; kb++) {
            float4 f0 = *(const float4*)(xrow + kb * 32 + quad * 8);
            float4 f1 = *(const float4*)(xrow + kb * 32 + quad * 8 + 4);
            bfu u;
            u.h[0] = f2b(f0.x); u.h[1] = f2b(f0.y); u.h[2] = f2b(f0.z); u.h[3] = f2b(f0.w);
            u.h[4] = f2b(f1.x); u.h[5] = f2b(f1.y); u.h[6] = f2b(f1.z); u.h[7] = f2b(f1.w);
            aX[kb] = u.v;
        }
    }

    const int cls = ((wh == 15) ? 2 : 0) + ((wwi == 15) ? 1 : 0);
    const bf16* bBc = sbB + (size_t)cls * 24576;
    bf16* sPw = sP + wave * 16 * 72;

    __syncthreads();                           // chunk0 + biases staged

    int pb = 0;
    for (int g = 0; g < 2; g++) {
        // ---- qkv for head group g: 9 chunks of 32 cols, 2-phase pipeline ----
        for (int c = 0; c < 9; c++) {
            if (c < 8)
                stage_lds(qkvTg + (size_t)(g * 320 + (c + 1) * 32) * 200,
                          sWb + (pb ^ 1) * 6400, 12800, t);
            else if (g == 0)
                stage_lds(qkvTg + (size_t)320 * 200,
                          sWb + (pb ^ 1) * 6400, 12800, t);
            const bf16* sW = sWb + pb * 6400;
            #pragma unroll
            for (int ct = 0; ct < 2; ct++) {
                int c0 = c * 32 + ct * 16;
                bfrag bw[6];
                #pragma unroll
                for (int kb = 0; kb < 6; kb++)
                    bw[kb] = *(const bfrag*)&sW[(ct * 16 + l15) * 200 + kb * 32 + quad * 8];
                ffrag acc = {0.f, 0.f, 0.f, 0.f};
                #pragma unroll
                for (int kb = 0; kb < 6; kb++) acc = MFMA(aX[kb], bw[kb], acc);
                float bias = sQB[g * 320 + c0 + l15];
                #pragma unroll
                for (int reg = 0; reg < 4; reg++) {
                    int r = r0 + quad * 4 + reg;
                    float v = acc[reg] + bias;
                    if (c0 < 96)       sQ[r * 104 + c0 + l15] = f2b(v);
                    else if (c0 < 192) sK[r * 104 + (c0 - 96) + l15] = f2b(v);
                    else               sVT[(c0 - 192 + l15) * 72 + r] = f2b(v);
                }
            }
            __syncthreads();                   // drains prefetch; chunk c+1 ready
            pb ^= 1;
        }
        // ---- attention heads g*3 .. g*3+2 (no staging in flight here) ----
        for (int hl = 0; hl < 3; hl++) {
            int h = g * 3 + hl;
            bfrag aQ = *(const bfrag*)&sQ[(r0 + l15) * 104 + hl * 32 + quad * 8];
            ffrag Sf[4];
            #pragma unroll
            for (int jt = 0; jt < 4; jt++) {
                bfrag bK = *(const bfrag*)&sK[(jt * 16 + l15) * 104 + hl * 32 + quad * 8];
                ffrag z = {0.f, 0.f, 0.f, 0.f};
                Sf[jt] = MFMA(aQ, bK, z);
            }
            const bf16* bb = bBc + h * 4096 + (r0 + quad * 4) * 64 + l15;
            #pragma unroll
            for (int jt = 0; jt < 4; jt++)
                #pragma unroll
                for (int reg = 0; reg < 4; reg++)
                    Sf[jt][reg] = Sf[jt][reg] * 0.1767766952966369f
                                + b2f(bb[reg * 64 + jt * 16]);
            #pragma unroll
            for (int reg = 0; reg < 4; reg++) {
                float m = fmaxf(fmaxf(Sf[0][reg], Sf[1][reg]), fmaxf(Sf[2][reg], Sf[3][reg]));
                m = fmaxf(m, __shfl_xor(m, 1)); m = fmaxf(m, __shfl_xor(m, 2));
                m = fmaxf(m, __shfl_xor(m, 4)); m = fmaxf(m, __shfl_xor(m, 8));
                float s = 0.f;
                #pragma unroll
                for (int jt = 0; jt < 4; jt++) { Sf[jt][reg] = __expf(Sf[jt][reg] - m); s += Sf[jt][reg]; }
                s += __shfl_xor(s, 1); s += __shfl_xor(s, 2);
                s += __shfl_xor(s, 4); s += __shfl_xor(s, 8);
                float inv = 1.f / s;
                int prow = (quad * 4 + reg) * 72;
                #pragma unroll
                for (int jt = 0; jt < 4; jt++)
                    sPw[prow + jt * 16 + l15] = f2b(Sf[jt][reg] * inv);
            }
            bfrag aP0 = *(const bfrag*)&sPw[l15 * 72 + quad * 8];
            bfrag aP1 = *(const bfrag*)&sPw[l15 * 72 + 32 + quad * 8];
            #pragma unroll
            for (int ct = 0; ct < 2; ct++) {
                bfrag bV0 = *(const bfrag*)&sVT[(hl * 32 + ct * 16 + l15) * 72 + quad * 8];
                bfrag bV1 = *(const bfrag*)&sVT[(hl * 32 + ct * 16 + l15) * 72 + 32 + quad * 8];
                ffrag z = {0.f, 0.f, 0.f, 0.f};
                ffrag o = MFMA(aP1, bV1, MFMA(aP0, bV0, z));
                #pragma unroll
                for (int reg = 0; reg < 4; reg++)
                    Og[((size_t)win * 64 + r0 + quad * 4 + reg) * 192 + h * 32 + ct * 16 + l15]
                        = f2b(o[reg]);
            }
        }
        __syncthreads();                       // attn reads done before g1 writes
    }
}

// ---------------------------------------------------------------------------
// k_proj: 128 rows (2 windows)/block, 4 waves x 32 rows (rt=2).
// projT staged ONCE (76800 B), 1 barrier. -> xres (reverse-shift + residual)
// ---------------------------------------------------------------------------
__global__ __launch_bounds__(256, 2) void k_proj(
    const float* __restrict__ x, const float* __restrict__ proj_b,
    const char* __restrict__ ws, float* __restrict__ xres)
{
    __shared__ __align__(16) bf16 sWp[192 * 200];   // 76800 B

    const bf16* projT = (const bf16*)(ws + WS_PROJT);
    const bf16* Og    = (const bf16*)(ws + WS_OG);

    const int t    = threadIdx.x;
    const int lane = t & 63, quad = lane >> 4, l15 = lane & 15;
    const int wave = t >> 6, r0 = wave * 32;
    const size_t row0 = (size_t)blockIdx.x * 128;

    stage_lds(projT, sWp, 76800, t);

    // A-frags of O (global, bf16, contiguous 16B)
    bfrag aO[2][6];
    #pragma unroll
    for (int rt = 0; rt < 2; rt++)
        #pragma unroll
        for (int kb = 0; kb < 6; kb++)
            aO[rt][kb] = *(const bfrag*)&Og[(row0 + r0 + rt * 16 + l15) * 192 + kb * 32 + quad * 8];

    // token scatter addresses (reverse shift)
    size_t tokb[2][4];
    #pragma unroll
    for (int rt = 0; rt < 2; rt++)
        #pragma unroll
        for (int reg = 0; reg < 4; reg++) {
            int n = r0 + rt * 16 + quad * 4 + reg;
            int w2 = (int)(blockIdx.x * 2) + (n >> 6);
            int nl = n & 63;
            int b = w2 >> 8, wi = w2 & 255;
            int wh = wi >> 4, wwi = wi & 15;
            int sr = wh * 8 + (nl >> 3), sc = wwi * 8 + (nl & 7);
            int h2 = (sr + 4) & 127, w2c = (sc + 4) & 127;
            tokb[rt][reg] = ((size_t)(b * 16384 + h2 * 128 + w2c)) * 192;
        }

    __syncthreads();

    ffrag acc[2][12];
    #pragma unroll
    for (int rt = 0; rt < 2; rt++)
        #pragma unroll
        for (int ct = 0; ct < 12; ct++)
            acc[rt][ct] = (ffrag){0.f, 0.f, 0.f, 0.f};

    #pragma unroll
    for (int ct = 0; ct < 12; ct++) {
        bfrag bw[6];
        #pragma unroll
        for (int kb = 0; kb < 6; kb++)
            bw[kb] = *(const bfrag*)&sWp[(ct * 16 + l15) * 200 + kb * 32 + quad * 8];
        #pragma unroll
        for (int rt = 0; rt < 2; rt++)
            #pragma unroll
            for (int kb = 0; kb < 6; kb++)
                acc[rt][ct] = MFMA(aO[rt][kb], bw[kb], acc[rt][ct]);
    }

    #pragma unroll
    for (int rt = 0; rt < 2; rt++)
        #pragma unroll
        for (int ct = 0; ct < 12; ct++) {
            int col = ct * 16 + l15;
            float pb = proj_b[col];
            #pragma unroll
            for (int reg = 0; reg < 4; reg++) {
                size_t gi = tokb[rt][reg] + col;
                xres[gi] = acc[rt][ct][reg] + pb + x[gi];
            }
        }
}

// ---------------------------------------------------------------------------
// k_mlp: 128 rows/block, 4 waves x 32 rows (rt=2). 24 chunks of 32 hidden,
// double-buffered w1/w2 staging with COUNTED vmcnt (8 loads/wave stay in
// flight across raw s_barrier; no compiler vmcnt(0) drain). LDS 69632.
// ---------------------------------------------------------------------------
__global__ __launch_bounds__(256, 2) void k_mlp(
    const float* __restrict__ xres, const float* __restrict__ g,
    const float* __restrict__ bb, const float* __restrict__ b1,
    const float* __restrict__ b2, const char* __restrict__ ws,
    float* __restrict__ out)
{
    __shared__ __align__(16) unsigned char smem[69632];
    bf16*  w1base = (bf16*)(smem);           // 2 x [32][200] (12800 B each)
    bf16*  w2base = (bf16*)(smem + 25600);   // 2 x [192][40] (15360 B each)
    bf16*  hS     = (bf16*)(smem + 56320);   // [4][32][40] (10240 B)
    float* sB1f   = (float*)(smem + 66560);  // [768] (3072 B)
    bf16*  U      = (bf16*)(smem);           // xn [128][200] (prologue only)

    const bf16* w1T = (const bf16*)(ws + WS_W1T);
    const bf16* w2T = (const bf16*)(ws + WS_W2T);

    const int t    = threadIdx.x;
    const int lane = t & 63, quad = lane >> 4, l15 = lane & 15;
    const int wave = t >> 6, r0 = wave * 32;
    const size_t row0 = (size_t)blockIdx.x * 128;

    stage_lds_q(b1, smem + 66560, 3072, t);  // b1 -> LDS (disjoint from xn)

    // ---- wave-local LayerNorm -> xn (bf16, U) ----
    #pragma unroll
    for (int p = 0; p < 2; p++) {
        int row = r0 + p * 16 + l15;
        const float4* src = (const float4*)(xres + (row0 + row) * 192 + quad * 48);
        float v[48];
        float s = 0.f, sq = 0.f;
        #pragma unroll
        for (int u = 0; u < 12; u++) {
            float4 f = src[u];
            v[u*4] = f.x; v[u*4+1] = f.y; v[u*4+2] = f.z; v[u*4+3] = f.w;
            s  += f.x + f.y + f.z + f.w;
            sq += f.x*f.x + f.y*f.y + f.z*f.z + f.w*f.w;
        }
        s  += __shfl_xor(s, 16);  s  += __shfl_xor(s, 32);
        sq += __shfl_xor(sq, 16); sq += __shfl_xor(sq, 32);
        float mean = s * (1.f / 192.f);
        float var  = sq * (1.f / 192.f) - mean * mean;
        float rstd = rsqrtf(var + 1e-5f);
        __hip_bfloat162* dst = (__hip_bfloat162*)&U[row * 200 + quad * 48];
        #pragma unroll
        for (int u = 0; u < 24; u++) {
            int c = quad * 48 + u * 2;
            float a0 = (v[u*2]   - mean) * rstd * g[c]     + bb[c];
            float a1 = (v[u*2+1] - mean) * rstd * g[c + 1] + bb[c + 1];
            dst[u] = __float22bfloat162_rn({a0, a1});
        }
    }

    // A-frags of xn (own rows; within-wave RAW)
    bfrag aX[2][6];
    #pragma unroll
    for (int rt = 0; rt < 2; rt++)
        #pragma unroll
        for (int kb = 0; kb < 6; kb++)
            aX[rt][kb] = *(const bfrag*)&U[(r0 + rt*16 + l15) * 200 + kb*32 + quad*8];

    __syncthreads();                         // everyone done reading xn region

    // stage chunk 0 (overlays xn region -- safe after barrier), then drain
    // once; after this the main loop never drains vmcnt to 0 until the tail.
    stage_lds_q(w1T, w1base, 12800, t);
    stage_lds_q(w2T, w2base, 15360, t);
    asm volatile("s_waitcnt vmcnt(0)" ::: "memory");
    __builtin_amdgcn_s_barrier();            // chunk 0 + b1 landed everywhere

    bf16* hs_w = hS + wave * 32 * 40;

    ffrag oacc[2][12];
    #pragma unroll
    for (int rt = 0; rt < 2; rt++)
        #pragma unroll
        for (int ct = 0; ct < 12; ct++)
            oacc[rt][ct] = (ffrag){0.f, 0.f, 0.f, 0.f};

    for (int kc = 0; kc < 24; kc++) {
        const int p = kc & 1;
        const bf16* w1c = w1base + p * 6400;
        const bf16* w2c = w2base + p * 7680;
        if (kc < 23) {
            // prefetch next chunk (4+4 loads/wave, uniform); wait only for the
            // PREVIOUS chunk's 8 loads -- the 8 just issued stay in flight.
            stage_lds_q(w1T + (size_t)(kc + 1) * 6400, w1base + (p ^ 1) * 6400, 12800, t);
            stage_lds_q(w2T + (size_t)(kc + 1) * 7680, w2base + (p ^ 1) * 7680, 15360, t);
            asm volatile("s_waitcnt vmcnt(8)" ::: "memory");
        } else {
            asm volatile("s_waitcnt vmcnt(0)" ::: "memory");
        }
        __builtin_amdgcn_s_barrier();        // all waves: chunk kc resident

        // MLP1 (32 hidden cols) + GELU -> hS (own rows)
        #pragma unroll
        for (int ct = 0; ct < 2; ct++) {
            bfrag bw[6];
            #pragma unroll
            for (int kb = 0; kb < 6; kb++)
                bw[kb] = *(const bfrag*)&w1c[(ct*16 + l15) * 200 + kb*32 + quad*8];
            float bias = sB1f[kc * 32 + ct * 16 + l15];
            #pragma unroll
            for (int rt = 0; rt < 2; rt++) {
                ffrag a = {0.f, 0.f, 0.f, 0.f};
                #pragma unroll
                for (int kb = 0; kb < 6; kb++) a = MFMA(aX[rt][kb], bw[kb], a);
                #pragma unroll
                for (int reg = 0; reg < 4; reg++)
                    hs_w[(rt*16 + quad*4 + reg) * 40 + ct*16 + l15] =
                        f2b(gelu_t(a[reg] + bias));
            }
        }
        // MLP2 over this 32-k chunk
        bfrag aH[2];
        #pragma unroll
        for (int rt = 0; rt < 2; rt++)
            aH[rt] = *(const bfrag*)&hs_w[(rt*16 + l15) * 40 + quad*8];
        #pragma unroll
        for (int ct = 0; ct < 12; ct++) {
            bfrag bw2 = *(const bfrag*)&w2c[(ct*16 + l15) * 40 + quad*8];
            #pragma unroll
            for (int rt = 0; rt < 2; rt++)
                oacc[rt][ct] = MFMA(aH[rt], bw2, oacc[rt][ct]);
        }
        __builtin_amdgcn_s_barrier();        // reads of buf p done before next
                                             // iteration stages into it
    }

    // ---- epilogue: out = xres + mlp + b2 ----
    #pragma unroll
    for (int rt = 0; rt < 2; rt++)
        #pragma unroll
        for (int ct = 0; ct < 12; ct++) {
            int col = ct * 16 + l15;
            float b2v = b2[col];
            #pragma unroll
            for (int reg = 0; reg < 4; reg++) {
                size_t gi = (row0 + r0 + rt*16 + quad*4 + reg) * 192 + col;
                out[gi] = xres[gi] + oacc[rt][ct][reg] + b2v;
            }
        }
}

// ---------------------------------------------------------------------------
extern "C" void kernel_launch(void* const* d_in, const int* in_sizes, int n_in,
                              void* d_out, int out_size, void* d_ws, size_t ws_size,
                              hipStream_t stream)
{
    (void)in_sizes; (void)n_in; (void)out_size; (void)ws_size;

    const float* x      = (const float*)d_in[0];
    const float* qkv_w  = (const float*)d_in[1];
    const float* qkv_b  = (const float*)d_in[2];
    const float* proj_w = (const float*)d_in[3];
    const float* proj_b = (const float*)d_in[4];
    const float* rpb    = (const float*)d_in[5];
    const float* n2g    = (const float*)d_in[6];
    const float* n2b    = (const float*)d_in[7];
    const float* w1     = (const float*)d_in[8];
    const float* b1     = (const float*)d_in[9];
    const float* w2     = (const float*)d_in[10];
    const float* b2     = (const float*)d_in[11];

    char*  ws   = (char*)d_ws;
    float* xres = (float*)(ws + WS_XRES);
    bf16*  Og   = (bf16*)(ws + WS_OG);
    float* out  = (float*)d_out;

    hipLaunchKernelGGL(k_prep, dim3(2357), dim3(256), 0, stream,
                       qkv_w, qkv_b, proj_w, w1, w2, rpb, ws);
    hipLaunchKernelGGL(k_attn, dim3(2048), dim3(256), 0, stream,
                       x, ws, Og);
    hipLaunchKernelGGL(k_proj, dim3(1024), dim3(256), 0, stream,
                       x, proj_b, ws, xres);
    hipLaunchKernelGGL(k_mlp,  dim3(1024), dim3(256), 0, stream,
                       xres, n2g, n2b, b1, b2, ws, out);
}